// Round 1
// baseline (1481.600 us; speedup 1.0000x reference)
//
#include <hip/hip_runtime.h>

#define N_NODES_C 100000
#define N_EDGES_C 1200000
#define NFEAT_C 64
#define NHID_C 256
#define NCLASS_C 40
#define ORDER_C 8

// ---------------- CSR build ----------------

static __global__ __launch_bounds__(256) void k_count(const int* __restrict__ rows,
                                                      int* __restrict__ cnt, int E)
{
    int i = blockIdx.x * 256 + threadIdx.x;
    if (i < E) atomicAdd(&cnt[rows[i]], 1);
}

static __global__ __launch_bounds__(256) void k_dinv(const int* __restrict__ cnt,
                                                     float* __restrict__ dinv, int n)
{
    int i = blockIdx.x * 256 + threadIdx.x;
    if (i < n) dinv[i] = rsqrtf((float)(cnt[i] + 1));  // +1 self-loop
}

// single-block exclusive prefix scan over cnt -> rp[0..n]
static __global__ __launch_bounds__(1024) void k_scan(const int* __restrict__ cnt,
                                                      int* __restrict__ rp, int n)
{
    __shared__ int sums[1024];
    int tid = threadIdx.x;
    int per = (n + 1023) >> 10;
    int beg = tid * per;
    int end = beg + per; if (end > n) end = n;
    int s = 0;
    for (int i = beg; i < end; ++i) s += cnt[i];
    sums[tid] = s;
    __syncthreads();
    // Hillis-Steele inclusive scan
    for (int off = 1; off < 1024; off <<= 1) {
        int v = (tid >= off) ? sums[tid - off] : 0;
        __syncthreads();
        sums[tid] += v;
        __syncthreads();
    }
    int run = (tid == 0) ? 0 : sums[tid - 1];
    for (int i = beg; i < end; ++i) { rp[i] = run; run += cnt[i]; }
    if (beg < n && end == n) rp[n] = run;
}

static __global__ __launch_bounds__(256) void k_scatter(const int* __restrict__ rows,
                                                        const int* __restrict__ cols,
                                                        const int* __restrict__ rp,
                                                        int* __restrict__ fill,
                                                        const float* __restrict__ dinv,
                                                        int* __restrict__ ccol,
                                                        float* __restrict__ cw, int E)
{
    int i = blockIdx.x * 256 + threadIdx.x;
    if (i < E) {
        int r = rows[i], c = cols[i];
        int pos = rp[r] + atomicAdd(&fill[r], 1);
        ccol[pos] = c;
        cw[pos] = dinv[c];  // full weight = dinv[r]*dinv[c]; dinv[r] applied at gather
    }
}

// ---------------- feature init: h = 0.5*x ; y = h ----------------

static __global__ __launch_bounds__(256) void k_init(const float4* __restrict__ x,
                                                     float4* __restrict__ h,
                                                     float4* __restrict__ y, int n4)
{
    int i = blockIdx.x * 256 + threadIdx.x;
    if (i < n4) {
        float4 v = x[i];
        v.x *= 0.5f; v.y *= 0.5f; v.z *= 0.5f; v.w *= 0.5f;
        h[i] = v; y[i] = v;
    }
}

// ---------------- SpMM: one wave per row, lane = feature ----------------
// out[i] = dinv[i] * ( sum_e dinv[col_e]*h[col_e] + dinv[i]*h[i] ) ; y += out

static __global__ __launch_bounds__(256) void k_spmm(const float* __restrict__ h,
                                                     float* __restrict__ h_out,
                                                     float* __restrict__ y,
                                                     const int* __restrict__ rp,
                                                     const int* __restrict__ ccol,
                                                     const float* __restrict__ cw,
                                                     const float* __restrict__ dinv, int n)
{
    int wave = (blockIdx.x * 256 + threadIdx.x) >> 6;
    int lane = threadIdx.x & 63;
    if (wave >= n) return;
    int s = rp[wave], e2 = rp[wave + 1];
    float acc = 0.f;
    for (int e = s; e < e2; ++e) {
        int c = ccol[e];
        float w = cw[e];
        acc = fmaf(w, h[(size_t)c * 64 + lane], acc);
    }
    float di = dinv[wave];
    size_t idx = (size_t)wave * 64 + lane;
    float v = di * fmaf(di, h[idx], acc);
    h_out[idx] = v;
    y[idx] += v;
}

// ---------------- fused MLP: out = relu((y/9) @ W1 + b1) @ W2 + b2 ----------------

#define BR 8

static __global__ __launch_bounds__(256) void k_mlp(const float* __restrict__ y,
                                                    const float* __restrict__ W1,
                                                    const float* __restrict__ b1,
                                                    const float* __restrict__ W2,
                                                    const float* __restrict__ b2,
                                                    float* __restrict__ out, int n)
{
    __shared__ float ys[BR][NFEAT_C];
    __shared__ float hs[BR][NHID_C];
    int tid = threadIdx.x;

    for (int base = blockIdx.x * BR; base < n; base += gridDim.x * BR) {
        int rows = n - base; if (rows > BR) rows = BR;
        // load y rows (scaled by 1/9)
        for (int i = tid; i < rows * NFEAT_C; i += 256) {
            int r = i >> 6, k = i & 63;
            ys[r][k] = y[(size_t)(base + r) * NFEAT_C + k] * (1.f / 9.f);
        }
        __syncthreads();
        // stage A: hid[r][tid] for all r
        float acc[BR];
        float bb = b1[tid];
        #pragma unroll
        for (int r = 0; r < BR; ++r) acc[r] = bb;
        for (int k = 0; k < NFEAT_C; ++k) {
            float w = W1[k * NHID_C + tid];
            #pragma unroll
            for (int r = 0; r < BR; ++r) acc[r] = fmaf(ys[r][k], w, acc[r]);
        }
        #pragma unroll
        for (int r = 0; r < BR; ++r) hs[r][tid] = fmaxf(acc[r], 0.f);
        __syncthreads();
        // stage B: out[r][c]
        for (int t = tid; t < rows * NCLASS_C; t += 256) {
            int r = t / NCLASS_C, c = t % NCLASS_C;
            float a = b2[c];
            #pragma unroll 8
            for (int k = 0; k < NHID_C; ++k) a = fmaf(hs[r][k], W2[k * NCLASS_C + c], a);
            out[(size_t)(base + r) * NCLASS_C + c] = a;
        }
        __syncthreads();
    }
}

// ---------------- launch ----------------

extern "C" void kernel_launch(void* const* d_in, const int* in_sizes, int n_in,
                              void* d_out, int out_size, void* d_ws, size_t ws_size,
                              hipStream_t stream)
{
    const float* x  = (const float*)d_in[0];
    const int*   ei = (const int*)d_in[1];
    const float* W1 = (const float*)d_in[2];
    const float* b1 = (const float*)d_in[3];
    const float* W2 = (const float*)d_in[4];
    const float* b2 = (const float*)d_in[5];
    float* out = (float*)d_out;

    const int n = N_NODES_C, E = N_EDGES_C;

    char* ws = (char*)d_ws;
    size_t off = 0;
    auto alloc = [&](size_t bytes) -> void* {
        void* p = ws + off;
        off = (off + bytes + 255) & ~(size_t)255;
        return p;
    };
    int*   cnt  = (int*)  alloc((size_t)n * 4);
    int*   fill = (int*)  alloc((size_t)n * 4);
    int*   rp   = (int*)  alloc((size_t)(n + 1) * 4);
    float* dinv = (float*)alloc((size_t)n * 4);
    int*   ccol = (int*)  alloc((size_t)E * 4);
    float* cw   = (float*)alloc((size_t)E * 4);
    float* ha   = (float*)alloc((size_t)n * NFEAT_C * 4);
    float* hb   = (float*)alloc((size_t)n * NFEAT_C * 4);
    float* y    = (float*)alloc((size_t)n * NFEAT_C * 4);

    hipMemsetAsync(cnt, 0, (size_t)n * 4, stream);
    hipMemsetAsync(fill, 0, (size_t)n * 4, stream);

    const int* rows = ei;
    const int* cols = ei + E;

    k_count  <<<(E + 255) / 256, 256, 0, stream>>>(rows, cnt, E);
    k_dinv   <<<(n + 255) / 256, 256, 0, stream>>>(cnt, dinv, n);
    k_scan   <<<1, 1024, 0, stream>>>(cnt, rp, n);
    k_scatter<<<(E + 255) / 256, 256, 0, stream>>>(rows, cols, rp, fill, dinv, ccol, cw, E);
    k_init   <<<(n * (NFEAT_C / 4) + 255) / 256, 256, 0, stream>>>((const float4*)x, (float4*)ha, (float4*)y, n * (NFEAT_C / 4));

    float* cur = ha;
    float* nxt = hb;
    for (int it = 0; it < ORDER_C; ++it) {
        k_spmm<<<(n * 64 + 255) / 256, 256, 0, stream>>>(cur, nxt, y, rp, ccol, cw, dinv, n);
        float* t = cur; cur = nxt; nxt = t;
    }

    k_mlp<<<2048, 256, 0, stream>>>(y, W1, b1, W2, b2, out, n);
}

// Round 2
// 948.838 us; speedup vs baseline: 1.5615x; 1.5615x over previous
//
#include <hip/hip_runtime.h>

#define NN 100000
#define NE 1200000
#define NF 64
#define NH 256
#define NC 40
#define ORDER_C 8

// ---------------- CSR build ----------------

static __global__ __launch_bounds__(256) void k_count(const int* __restrict__ rows,
                                                      int* __restrict__ cnt, int E)
{
    int i = blockIdx.x * 256 + threadIdx.x;
    if (i < E) atomicAdd(&cnt[rows[i]], 1);
}

static __global__ __launch_bounds__(256) void k_dinv(const int* __restrict__ cnt,
                                                     float* __restrict__ dinv, int n)
{
    int i = blockIdx.x * 256 + threadIdx.x;
    if (i < n) dinv[i] = rsqrtf((float)(cnt[i] + 1));  // +1 self-loop
}

// single-block exclusive prefix scan over cnt -> rp[0..n]
static __global__ __launch_bounds__(1024) void k_scan(const int* __restrict__ cnt,
                                                      int* __restrict__ rp, int n)
{
    __shared__ int sums[1024];
    int tid = threadIdx.x;
    int per = (n + 1023) >> 10;
    int beg = tid * per;
    int end = beg + per; if (end > n) end = n;
    int s = 0;
    for (int i = beg; i < end; ++i) s += cnt[i];
    sums[tid] = s;
    __syncthreads();
    for (int off = 1; off < 1024; off <<= 1) {
        int v = (tid >= off) ? sums[tid - off] : 0;
        __syncthreads();
        sums[tid] += v;
        __syncthreads();
    }
    int run = (tid == 0) ? 0 : sums[tid - 1];
    for (int i = beg; i < end; ++i) { rp[i] = run; run += cnt[i]; }
    if (beg < n && end == n) rp[n] = run;
}

static __global__ __launch_bounds__(256) void k_scatter(const int* __restrict__ rows,
                                                        const int* __restrict__ cols,
                                                        const int* __restrict__ rp,
                                                        int* __restrict__ fill,
                                                        const float* __restrict__ dinv,
                                                        int2* __restrict__ colw, int E)
{
    int i = blockIdx.x * 256 + threadIdx.x;
    if (i < E) {
        int r = rows[i], c = cols[i];
        int pos = rp[r] + atomicAdd(&fill[r], 1);
        colw[pos] = make_int2(c, __float_as_int(dinv[c]));
    }
}

// ---------------- feature init: h = 0.5*x ; y = h ----------------

static __global__ __launch_bounds__(256) void k_init(const float4* __restrict__ x,
                                                     float4* __restrict__ h,
                                                     float4* __restrict__ y, int n4)
{
    int i = blockIdx.x * 256 + threadIdx.x;
    if (i < n4) {
        float4 v = x[i];
        v.x *= 0.5f; v.y *= 0.5f; v.z *= 0.5f; v.w *= 0.5f;
        h[i] = v; y[i] = v;
    }
}

// ---------------- SpMM: one wave per row, 16 lanes x float4, 4 edges in flight ----

static __global__ __launch_bounds__(256) void k_spmm(const float4* __restrict__ h4,
                                                     float4* __restrict__ ho4,
                                                     float4* __restrict__ y4,
                                                     const int* __restrict__ rp,
                                                     const int2* __restrict__ colw,
                                                     const float* __restrict__ dinv, int n)
{
    int wave = (blockIdx.x * 256 + threadIdx.x) >> 6;
    int lane = threadIdx.x & 63;
    if (wave >= n) return;
    int f = lane & 15;   // float4 slot within the 64-feature row
    int q = lane >> 4;   // edge slot (4 edges concurrently)
    int s = rp[wave], e = rp[wave + 1];
    float4 acc = make_float4(0.f, 0.f, 0.f, 0.f);
    for (int i = s + q; i < e; i += 4) {
        int2 cw = colw[i];
        float w = __int_as_float(cw.y);
        float4 hv = h4[cw.x * 16 + f];
        acc.x = fmaf(w, hv.x, acc.x);
        acc.y = fmaf(w, hv.y, acc.y);
        acc.z = fmaf(w, hv.z, acc.z);
        acc.w = fmaf(w, hv.w, acc.w);
    }
    // reduce the 4 edge slots (lanes differing in bits 4,5)
    acc.x += __shfl_xor(acc.x, 16); acc.y += __shfl_xor(acc.y, 16);
    acc.z += __shfl_xor(acc.z, 16); acc.w += __shfl_xor(acc.w, 16);
    acc.x += __shfl_xor(acc.x, 32); acc.y += __shfl_xor(acc.y, 32);
    acc.z += __shfl_xor(acc.z, 32); acc.w += __shfl_xor(acc.w, 32);
    if (q == 0) {
        float di = dinv[wave];
        int idx = wave * 16 + f;
        float4 hs = h4[idx];
        float4 v;
        v.x = di * fmaf(di, hs.x, acc.x);
        v.y = di * fmaf(di, hs.y, acc.y);
        v.z = di * fmaf(di, hs.z, acc.z);
        v.w = di * fmaf(di, hs.w, acc.w);
        ho4[idx] = v;
        float4 yv = y4[idx];
        yv.x += v.x; yv.y += v.y; yv.z += v.z; yv.w += v.w;
        y4[idx] = yv;
    }
}

// ---------------- transpose y -> yT[64][NN], folding the 1/9 scale ----------------

static __global__ __launch_bounds__(256) void k_transpose(const float* __restrict__ y,
                                                          float* __restrict__ yT, int n)
{
    __shared__ float t[64][65];
    int rb = blockIdx.x * 64;
    int lk = threadIdx.x & 63;
    int g  = threadIdx.x >> 6;  // 0..3
    for (int rr = g; rr < 64; rr += 4) {
        int r = rb + rr;
        t[rr][lk] = (r < n) ? y[(size_t)r * 64 + lk] * (1.f / 9.f) : 0.f;
    }
    __syncthreads();
    int r = rb + lk;
    for (int kk = g; kk < 64; kk += 4) {
        if (r < n) yT[(size_t)kk * n + r] = t[lk][kk];
    }
}

// ---------------- fused MLP: thread = row, weights via scalar loads ----------------
// out[row] = relu(yrow @ W1 + b1) @ W2 + b2, yrow pre-scaled by 1/9 (in yT)

static __global__ __launch_bounds__(64) void k_mlp(const float* __restrict__ yT,
                                                   const float* __restrict__ W1,
                                                   const float* __restrict__ b1,
                                                   const float* __restrict__ W2,
                                                   const float* __restrict__ b2,
                                                   float* __restrict__ out, int n)
{
    __shared__ float outs[64 * 41];
    int lane = threadIdx.x;
    int row = blockIdx.x * 64 + lane;
    bool valid = row < n;

    float o[NC];
    #pragma unroll
    for (int j = 0; j < NC; ++j) o[j] = b2[j];

    for (int p = 0; p < 8; ++p) {          // hidden-chunk c0 = 32*p
        int c0 = p * 32;
        float acc[32];
        #pragma unroll
        for (int c = 0; c < 32; ++c) acc[c] = b1[c0 + c];
        for (int kb = 0; kb < 8; ++kb) {   // k-chunk of 8
            float yv[8];
            #pragma unroll
            for (int j = 0; j < 8; ++j)
                yv[j] = valid ? yT[(size_t)(kb * 8 + j) * n + row] : 0.f;
            #pragma unroll
            for (int j = 0; j < 8; ++j) {
                const float* w1r = &W1[(size_t)(kb * 8 + j) * NH + c0];
                #pragma unroll
                for (int c = 0; c < 32; ++c)
                    acc[c] = fmaf(yv[j], w1r[c], acc[c]);
            }
        }
        #pragma unroll
        for (int c = 0; c < 32; ++c) {
            float hv = fmaxf(acc[c], 0.f);
            const float* w2r = &W2[(size_t)(c0 + c) * NC];
            #pragma unroll
            for (int j = 0; j < NC; ++j)
                o[j] = fmaf(hv, w2r[j], o[j]);
        }
    }

    #pragma unroll
    for (int j = 0; j < NC; ++j) outs[lane * 41 + j] = o[j];
    __syncthreads();
    size_t base = (size_t)blockIdx.x * 64 * NC;
    for (int t = lane; t < 64 * NC; t += 64) {
        int r = t / NC, j = t - r * NC;
        int grow = blockIdx.x * 64 + r;
        if (grow < n) out[(size_t)grow * NC + j] = outs[r * 41 + j];
    }
}

// ---------------- launch ----------------

extern "C" void kernel_launch(void* const* d_in, const int* in_sizes, int n_in,
                              void* d_out, int out_size, void* d_ws, size_t ws_size,
                              hipStream_t stream)
{
    const float* x  = (const float*)d_in[0];
    const int*   ei = (const int*)d_in[1];
    const float* W1 = (const float*)d_in[2];
    const float* b1 = (const float*)d_in[3];
    const float* W2 = (const float*)d_in[4];
    const float* b2 = (const float*)d_in[5];
    float* out = (float*)d_out;

    const int n = NN, E = NE;

    char* ws = (char*)d_ws;
    size_t off = 0;
    auto alloc = [&](size_t bytes) -> void* {
        void* p = ws + off;
        off = (off + bytes + 255) & ~(size_t)255;
        return p;
    };
    int*   cnt  = (int*)  alloc((size_t)n * 4);
    int*   fill = (int*)  alloc((size_t)n * 4);
    int*   rp   = (int*)  alloc((size_t)(n + 1) * 4);
    float* dinv = (float*)alloc((size_t)n * 4);
    int2*  colw = (int2*) alloc((size_t)E * 8);
    float* ha   = (float*)alloc((size_t)n * NF * 4);
    float* hb   = (float*)alloc((size_t)n * NF * 4);
    float* y    = (float*)alloc((size_t)n * NF * 4);

    hipMemsetAsync(cnt, 0, (size_t)n * 4, stream);
    hipMemsetAsync(fill, 0, (size_t)n * 4, stream);

    const int* rows = ei;
    const int* cols = ei + E;

    k_count  <<<(E + 255) / 256, 256, 0, stream>>>(rows, cnt, E);
    k_dinv   <<<(n + 255) / 256, 256, 0, stream>>>(cnt, dinv, n);
    k_scan   <<<1, 1024, 0, stream>>>(cnt, rp, n);
    k_scatter<<<(E + 255) / 256, 256, 0, stream>>>(rows, cols, rp, fill, dinv, colw, E);
    k_init   <<<(n * (NF / 4) + 255) / 256, 256, 0, stream>>>((const float4*)x, (float4*)ha, (float4*)y, n * (NF / 4));

    float* cur = ha;
    float* nxt = hb;
    for (int it = 0; it < ORDER_C; ++it) {
        k_spmm<<<(n * 64 + 255) / 256, 256, 0, stream>>>((const float4*)cur, (float4*)nxt,
                                                         (float4*)y, rp, colw, dinv, n);
        float* t = cur; cur = nxt; nxt = t;
    }

    // ha/hb are dead now; reuse hb for the transposed (and pre-scaled) y
    float* yT = hb;
    k_transpose<<<(n + 63) / 64, 256, 0, stream>>>(y, yT, n);
    k_mlp<<<(n + 63) / 64, 64, 0, stream>>>(yT, W1, b1, W2, b2, out, n);
}